// Round 12
// baseline (647.141 us; speedup 1.0000x reference)
//
#include <hip/hip_runtime.h>
#include <math.h>

#define D 64
#define H 128
#define KIN 8
#define KOUT 4
#define ELD16 72               // eins row stride bf16 (144B)
#define XLDB 136               // row stride bf16 (272B: 2-way b128 reads, free)
#define CHROWS 64              // MLP rows per chunk
#define MLPGRID 768            // persistent blocks (3 per CU)

typedef __attribute__((ext_vector_type(8))) short short8v;  // 8 bf16 = 4 VGPR
typedef __attribute__((ext_vector_type(4))) float f32x4;

__device__ inline unsigned short f2bf(float f) {            // RNE float->bf16
    union { float f; unsigned u; } v; v.f = f;
    unsigned r = v.u + 0x7FFF + ((v.u >> 16) & 1);
    return (unsigned short)(r >> 16);
}

// ---- weight pre-conversion: W0,W1 (fp32, 128x128 each) -> bf16 in ws ----
__global__ void convert_w_kernel(const float* __restrict__ W0,
                                 const float* __restrict__ W1,
                                 unsigned short* __restrict__ Wbf) {
    const int i = blockIdx.x * 256 + threadIdx.x;           // 0 .. 32767
    const float v = (i < H*H) ? W0[i] : W1[i - H*H];
    Wbf[i] = f2bf(v);
}

// ================= Kernel A: attention -> pooled[chunk][64] bf16 ============
// one wave = 2 nodes, no __syncthreads, MFMA scores (measured ~120us, on-pred)
__global__ __launch_bounds__(256, 6) void attn_kernel(
    const float* __restrict__ edges,
    const int*   __restrict__ in_idx,
    const int*   __restrict__ in_mask,
    unsigned short* __restrict__ pooled,   // [nodeEnd-nodeBase][64] bf16
    int nodeBase, int nodeEnd)
{
    __shared__ __align__(16) unsigned short eins[4][16][ELD16]; // 9216 B
    const int tid  = threadIdx.x;
    const int wave = tid >> 6;
    const int lane = tid & 63;
    const int col  = lane & 15;
    const int grp  = lane >> 4;
    const int n0   = nodeBase + blockIdx.x * 8 + wave * 2;
    if (n0 >= nodeEnd) return;             // wave-uniform

    const int   idx_l = in_idx [(size_t)n0*KIN + col];   // 16 idx = 2 nodes
    const float mkcol = (float)in_mask[(size_t)n0*KIN + col];

    float ein_r[16];
    #pragma unroll
    for (int r = 0; r < 16; ++r)
        ein_r[r] = edges[(size_t)__shfl(idx_l, r) * D + lane];
    #pragma unroll
    for (int r = 0; r < 16; ++r) eins[wave][r][lane] = f2bf(ein_r[r]);

    const short8v f0 = *(const short8v*)&eins[wave][col][grp*8];
    const short8v f1 = *(const short8v*)&eins[wave][col][32 + grp*8];
    f32x4 sc = (f32x4){0.f, 0.f, 0.f, 0.f};
    sc = __builtin_amdgcn_mfma_f32_16x16x32_bf16(f0, f0, sc, 0, 0, 0);
    sc = __builtin_amdgcn_mfma_f32_16x16x32_bf16(f1, f1, sc, 0, 0, 0);

    float s0, s1, s2, s3;
    {
        const bool kv = (mkcol > 0.f);
        #define MSK(jj, sv) { const int row = grp*4 + jj; \
            const bool ok = kv && ((row < 8) == (col < 8)); \
            sv = ok ? sc[jj] * 0.125f : -1e9f; }
        MSK(0, s0) MSK(1, s1) MSK(2, s2) MSK(3, s3)
        #undef MSK
    }
    float m0=s0, m1=s1, m2=s2, m3=s3;
    #pragma unroll
    for (int off = 1; off < 16; off <<= 1) {
        m0 = fmaxf(m0, __shfl_xor(m0, off));
        m1 = fmaxf(m1, __shfl_xor(m1, off));
        m2 = fmaxf(m2, __shfl_xor(m2, off));
        m3 = fmaxf(m3, __shfl_xor(m3, off));
    }
    float e0=__expf(s0-m0), e1=__expf(s1-m1), e2=__expf(s2-m2), e3=__expf(s3-m3);
    float t0=e0, t1=e1, t2=e2, t3=e3;
    #pragma unroll
    for (int off = 1; off < 16; off <<= 1) {
        t0 += __shfl_xor(t0, off); t1 += __shfl_xor(t1, off);
        t2 += __shfl_xor(t2, off); t3 += __shfl_xor(t3, off);
    }
    float wsum = __shfl(mkcol, grp*4 + 0) * (e0 / t0)
               + __shfl(mkcol, grp*4 + 1) * (e1 / t1)
               + __shfl(mkcol, grp*4 + 2) * (e2 / t2)
               + __shfl(mkcol, grp*4 + 3) * (e3 / t3);
    wsum += __shfl_xor(wsum, 16);
    wsum += __shfl_xor(wsum, 32);

    float dn = mkcol;
    dn += __shfl_xor(dn, 1); dn += __shfl_xor(dn, 2); dn += __shfl_xor(dn, 4);
    const float dnA = fmaxf(__shfl(dn, 0), 1.f);
    const float dnB = fmaxf(__shfl(dn, 8), 1.f);

    float pA = 0.f, pB = 0.f;
    #pragma unroll
    for (int k = 0; k < 8; ++k) {
        pA += __shfl(wsum, k)     * ein_r[k];
        pB += __shfl(wsum, 8 + k) * ein_r[8 + k];
    }
    const size_t pbase = (size_t)(n0 - nodeBase) * D;
    pooled[pbase + lane]     = f2bf(pA / dnA);   // node n0
    pooled[pbase + D + lane] = f2bf(pB / dnB);   // node n0+1
}

// ============ Kernel B: persistent MLP, weights-in-registers ================
// 768 blocks x 16ish chunks of 64 rows; double-buffered staging; h1 never
// touches LDS (reduced in-register against Wout).
__global__ __launch_bounds__(256, 3) void mlp_kernel(
    const float* __restrict__ edges,
    const int*   __restrict__ out_idx,
    const int*   __restrict__ out_mask,
    const float* __restrict__ b0, const float* __restrict__ b1,
    const float* __restrict__ Wout, const float* __restrict__ bout,
    const unsigned short* __restrict__ Wbf,     // [2][128][128] bf16
    const unsigned short* __restrict__ pooled,  // chunk-local
    float* __restrict__ out,
    int nodeBase, int nodeEnd)
{
    __shared__ __align__(16) unsigned short xbuf[2][CHROWS][XLDB]; // 34816 B
    __shared__ __align__(16) unsigned short h0buf[CHROWS][XLDB];   // 17408 B
    __shared__ float ypart[4][CHROWS];                             //  1024 B

    const int tid  = threadIdx.x;
    const int wave = tid >> 6;
    const int lane = tid & 63;
    const int l15  = lane & 15;
    const int grp  = lane >> 4;
    const int kofs = grp * 8;
    const int colb = wave * 32;            // wave owns cols [colb, colb+32)

    const int rowBeg = nodeBase * KOUT;
    const int rowEnd = nodeEnd * KOUT;
    const int nch = (rowEnd - rowBeg + CHROWS - 1) / CHROWS;

    // ---- persistent per-wave weight fragments (both layers) + scalars ------
    short8v w0[2][4], w1[2][4];            // [ct][ks], fully unrolled use only
    #pragma unroll
    for (int ct = 0; ct < 2; ++ct)
        #pragma unroll
        for (int ks = 0; ks < 4; ++ks) {
            w0[ct][ks] = *(const short8v*)&Wbf[(size_t)(colb + ct*16 + l15)*H + ks*32 + kofs];
            w1[ct][ks] = *(const short8v*)&Wbf[(size_t)H*H + (size_t)(colb + ct*16 + l15)*H + ks*32 + kofs];
        }
    const float bias0[2] = { b0[colb + l15], b0[colb + 16 + l15] };
    const float bias1[2] = { b1[colb + l15], b1[colb + 16 + l15] };
    const float wo[2]    = { Wout[colb + l15], Wout[colb + 16 + l15] };
    const float bo = bout[0];

    float ev[16];                          // staged edge values (next chunk)
    unsigned short pv[16];                 // staged pooled bf16 (next chunk)

    #define ISSUE(cc) do { \
        const int crb_ = rowBeg + (cc) * CHROWS; \
        _Pragma("unroll") \
        for (int rr = 0; rr < 16; ++rr) { \
            const int grow_ = crb_ + wave*16 + rr; \
            int oi_ = 0, nd_ = nodeBase; \
            if (grow_ < rowEnd) { oi_ = out_idx[grow_]; nd_ = grow_ >> 2; } \
            ev[rr] = edges[(size_t)oi_ * D + lane]; \
            pv[rr] = pooled[(size_t)(nd_ - nodeBase) * D + lane]; \
        } } while (0)
    #define WRITE(buf_) do { \
        _Pragma("unroll") \
        for (int rr = 0; rr < 16; ++rr) { \
            const int row_ = wave*16 + rr; \
            xbuf[buf_][row_][lane]     = f2bf(ev[rr]); \
            xbuf[buf_][row_][D + lane] = pv[rr]; \
        } } while (0)

    int c   = blockIdx.x;
    int cur = 0;
    if (c < nch) { ISSUE(c); WRITE(0); }
    __syncthreads();

    for (; c < nch; c += gridDim.x) {
        const int crb   = rowBeg + c * CHROWS;
        const int cnext = c + gridDim.x;

        // 1. issue next chunk's gathers (latency hides under MFMA below)
        if (cnext < nch) ISSUE(cnext);

        // 2. layer 0: acc = x . W0^T + b0  (A from xbuf[cur], B in regs)
        f32x4 acc[4][2];
        #pragma unroll
        for (int rt = 0; rt < 4; ++rt)
            #pragma unroll
            for (int ct = 0; ct < 2; ++ct) {
                const float bv = bias0[ct];
                acc[rt][ct] = (f32x4){bv, bv, bv, bv};
            }
        #pragma unroll
        for (int ks = 0; ks < 4; ++ks) {
            short8v a[4];
            #pragma unroll
            for (int rt = 0; rt < 4; ++rt)
                a[rt] = *(const short8v*)&xbuf[cur][rt*16 + l15][ks*32 + kofs];
            #pragma unroll
            for (int rt = 0; rt < 4; ++rt)
                #pragma unroll
                for (int ct = 0; ct < 2; ++ct)
                    acc[rt][ct] = __builtin_amdgcn_mfma_f32_16x16x32_bf16(a[rt], w0[ct][ks], acc[rt][ct], 0, 0, 0);
        }

        // 3. h0 = relu(acc) -> h0buf (wave writes its own 32-col slice)
        #pragma unroll
        for (int rt = 0; rt < 4; ++rt)
            #pragma unroll
            for (int ct = 0; ct < 2; ++ct)
                #pragma unroll
                for (int j = 0; j < 4; ++j)
                    h0buf[rt*16 + grp*4 + j][colb + ct*16 + l15] =
                        f2bf(fmaxf(acc[rt][ct][j], 0.f));
        __syncthreads();                       // h0 visible to all waves

        // 4. layer 1: acc = h0 . W1^T + b1
        #pragma unroll
        for (int rt = 0; rt < 4; ++rt)
            #pragma unroll
            for (int ct = 0; ct < 2; ++ct) {
                const float bv = bias1[ct];
                acc[rt][ct] = (f32x4){bv, bv, bv, bv};
            }
        #pragma unroll
        for (int ks = 0; ks < 4; ++ks) {
            short8v a[4];
            #pragma unroll
            for (int rt = 0; rt < 4; ++rt)
                a[rt] = *(const short8v*)&h0buf[rt*16 + l15][ks*32 + kofs];
            #pragma unroll
            for (int rt = 0; rt < 4; ++rt)
                #pragma unroll
                for (int ct = 0; ct < 2; ++ct)
                    acc[rt][ct] = __builtin_amdgcn_mfma_f32_16x16x32_bf16(a[rt], w1[ct][ks], acc[rt][ct], 0, 0, 0);
        }

        // 5. epilogue: y_partial = relu(acc1) . Wout over this wave's 32 cols
        #pragma unroll
        for (int rt = 0; rt < 4; ++rt) {
            #pragma unroll
            for (int j = 0; j < 4; ++j) {
                float p = fmaxf(acc[rt][0][j], 0.f) * wo[0]
                        + fmaxf(acc[rt][1][j], 0.f) * wo[1];
                p += __shfl_xor(p, 1);
                p += __shfl_xor(p, 2);
                p += __shfl_xor(p, 4);
                p += __shfl_xor(p, 8);
                if (l15 == 0) ypart[wave][rt*16 + grp*4 + j] = p;
            }
        }
        __syncthreads();                       // ypart ready
        if (tid < CHROWS) {
            const int grow = crb + tid;
            if (grow < rowEnd) {
                const float y = ypart[0][tid] + ypart[1][tid]
                              + ypart[2][tid] + ypart[3][tid] + bo;
                out[grow] = y * (float)out_mask[grow];
            }
        }

        // 6. commit staged next chunk into the other buffer
        if (cnext < nch) WRITE(cur ^ 1);
        __syncthreads();                       // next buf ready / reads done
        cur ^= 1;
    }
    #undef ISSUE
    #undef WRITE
}

extern "C" void kernel_launch(void* const* d_in, const int* in_sizes, int n_in,
                              void* d_out, int out_size, void* d_ws, size_t ws_size,
                              hipStream_t stream)
{
    const float* edges  = (const float*)d_in[0];
    const int* in_idx   = (const int*)d_in[1];
    const int* in_mask  = (const int*)d_in[2];
    const int* out_idx  = (const int*)d_in[3];
    const int* out_mask = (const int*)d_in[4];
    const float* W0   = (const float*)d_in[5];
    const float* b0   = (const float*)d_in[6];
    const float* W1   = (const float*)d_in[7];
    const float* b1   = (const float*)d_in[8];
    const float* Wout = (const float*)d_in[9];
    const float* bout = (const float*)d_in[10];
    float* out = (float*)d_out;

    unsigned short* Wbf       = (unsigned short*)d_ws;                  // 64 KB
    unsigned short* pooledBuf = (unsigned short*)((char*)d_ws + 65536);

    const int nNodes = in_sizes[1] / KIN;               // 200000
    convert_w_kernel<<<(2*H*H + 255) / 256, 256, 0, stream>>>(W0, W1, Wbf);

    // chunk nodes so pooled fits in remaining ws (128 B/node); usually 1 chunk
    const size_t avail = (ws_size > 65536) ? ws_size - 65536 : 0;
    long long maxNodes = (long long)(avail / (D * sizeof(unsigned short)));
    int chunk = (int)((maxNodes / 32) * 32);
    if (chunk <= 0) chunk = 32;
    if (chunk > nNodes) chunk = nNodes;

    for (int base = 0; base < nNodes; base += chunk) {
        const int end = (base + chunk < nNodes) ? base + chunk : nNodes;
        const int cn  = end - base;
        attn_kernel<<<(cn + 7) / 8, 256, 0, stream>>>(
            edges, in_idx, in_mask, pooledBuf, base, end);
        mlp_kernel<<<MLPGRID, 256, 0, stream>>>(
            edges, out_idx, out_mask, b0, b1, Wout, bout,
            Wbf, pooledBuf, out, base, end);
    }
}